// Round 2
// baseline (244.666 us; speedup 1.0000x reference)
//
#include <hip/hip_runtime.h>
#include <hip/hip_bf16.h>
#include <cstdint>
#include <cstddef>

#define B_  2
#define T_  4096
#define D_  768
#define H_  12
#define HD_ 64
#define M_  (B_*T_)   // 8192 rows

#define SCL 0.18033688f   // (1/sqrt(64)) * log2(e): folded into K projection

typedef __bf16 bf16x8 __attribute__((ext_vector_type(8)));
typedef float  f32x4  __attribute__((ext_vector_type(4)));
typedef short  s16x4  __attribute__((ext_vector_type(4)));
using bf16 = __hip_bfloat16;

__device__ inline float fexp2(float x) {
  float r; asm("v_exp_f32 %0, %1" : "=v"(r) : "v"(x)); return r;
}
__device__ inline uint32_t fu(float x) { union { float f; uint32_t u; } c; c.f = x; return c.u; }
__device__ inline uint32_t pktr(float a, float b) {   // truncated bf16 pair, 1 v_perm
  return __builtin_amdgcn_perm(fu(b), fu(a), 0x07060302);
}
// K=16 bf16 MFMA: B-operand fragment layout == swapped-QK^T C layout (k=qd*4+e),
// so P feeds PV straight from registers (no LDS transpose round trip).
__device__ inline f32x4 mfma16(s16x4 a, s16x4 b, f32x4 c) {
#if __has_builtin(__builtin_amdgcn_mfma_f32_16x16x16bf16_1k)
  return __builtin_amdgcn_mfma_f32_16x16x16bf16_1k(a, b, c, 0, 0, 0);
#else
  asm("v_mfma_f32_16x16x16_bf16 %0, %1, %2, %0" : "+v"(c) : "v"(a), "v"(b));
  return c;
#endif
}
#define GLD16(g, l) __builtin_amdgcn_global_load_lds( \
    (const __attribute__((address_space(1))) uint32_t*)(const void*)(g), \
    (__attribute__((address_space(3))) uint32_t*)(void*)(l), 16, 0, 0)

// ---------------- fp32 -> bf16 conversion (x + 4 weights, exact 1D grid) ---------
__global__ void cvt_all(const float* __restrict__ x,
                        const float* __restrict__ w0, const float* __restrict__ w1,
                        const float* __restrict__ w2, const float* __restrict__ w3,
                        bf16* __restrict__ xd,
                        bf16* __restrict__ d0, bf16* __restrict__ d1,
                        bf16* __restrict__ d2, bf16* __restrict__ d3) {
  int blk = blockIdx.x;
  const float* s; bf16* d; int i;
  if (blk < 6144) {                       // x: 6144*256 == M*D/4 exactly
    s = x; d = xd; i = blk * 256 + threadIdx.x;
  } else {                                // weights: 576*256 == D*D/4 exactly
    int q = blk - 6144, which = q / 576, rb = q % 576;
    switch (which) {
      case 0: s = w0; d = d0; break;
      case 1: s = w1; d = d1; break;
      case 2: s = w2; d = d2; break;
      default: s = w3; d = d3; break;
    }
    i = rb * 256 + threadIdx.x;
  }
  float4 v = ((const float4*)s)[i];
  union { bf16 o[4]; uint2 u; } pk;
  pk.o[0] = __float2bfloat16(v.x); pk.o[1] = __float2bfloat16(v.y);
  pk.o[2] = __float2bfloat16(v.z); pk.o[3] = __float2bfloat16(v.w);
  *(uint2*)(d + 4 * (size_t)i) = pk.u;
}

// ---------------- unified QKV GEMM, single K-loop path ---------------------------
__global__ __launch_bounds__(256) void gemm_qkv(const bf16* __restrict__ x,
                                                const bf16* __restrict__ W0,
                                                const bf16* __restrict__ W1,
                                                const bf16* __restrict__ W2,
                                                bf16* __restrict__ O0,
                                                bf16* __restrict__ O1,
                                                bf16* __restrict__ O2t) {
  __shared__ bf16 As[2][4096];
  __shared__ bf16 Bs[2][4096];
  const int flat = blockIdx.x;
  const int by = flat / 18;            // token tile (m)
  const int rr = flat % 18;
  const int z  = rr / 6;
  const int bx = rr % 6;               // feature tile (n)
  const bf16* Wz = (z == 0) ? W0 : ((z == 1) ? W1 : W2);
  const char* Ap; const char* Bp; int a0, b0;
  if (z == 2) { Ap = (const char*)x;  a0 = by * 128; Bp = (const char*)Wz; b0 = bx * 128; }
  else        { Ap = (const char*)Wz; a0 = bx * 128; Bp = (const char*)x;  b0 = by * 128; }
  const int t = threadIdx.x;
  const int w = t >> 6, lane = t & 63;
  const int wa = (w >> 1) * 64, wb = (w & 1) * 64;
  const int mi = lane & 15, qd = lane >> 4;

  int aoff[2], boff[2];
  #pragma unroll
  for (int i = 0; i < 2; ++i) {
    int L = i * 256 + t;
    int row = L >> 2, sl = L & 3, c = sl ^ (row & 3);
    aoff[i] = (a0 + row) * 1536 + c * 16;
    boff[i] = (b0 + row) * 1536 + c * 16;
  }
  const int fsw = (qd ^ (mi & 3)) * 8;

  f32x4 acc[4][4] = {};

  #pragma unroll
  for (int i = 0; i < 2; ++i) {
    GLD16(Ap + aoff[i], &As[0][i * 2048 + w * 512]);
    GLD16(Bp + boff[i], &Bs[0][i * 2048 + w * 512]);
  }

  for (int kk = 0; kk < 24; ++kk) {
    __syncthreads();
    const int par = kk & 1;
    if (kk + 1 < 24) {
      const int np = par ^ 1, kb = (kk + 1) * 64;
      #pragma unroll
      for (int i = 0; i < 2; ++i) {
        GLD16(Ap + aoff[i] + kb, &As[np][i * 2048 + w * 512]);
        GLD16(Bp + boff[i] + kb, &Bs[np][i * 2048 + w * 512]);
      }
    }
    bf16x8 af[4], bfr[4];
    #pragma unroll
    for (int at = 0; at < 4; ++at)
      af[at] = *(const bf16x8*)&As[par][(wa + at * 16 + mi) * 32 + fsw];
    #pragma unroll
    for (int bt = 0; bt < 4; ++bt)
      bfr[bt] = *(const bf16x8*)&Bs[par][(wb + bt * 16 + mi) * 32 + fsw];
    #pragma unroll
    for (int at = 0; at < 4; ++at)
      #pragma unroll
      for (int bt = 0; bt < 4; ++bt)
        acc[at][bt] = __builtin_amdgcn_mfma_f32_16x16x32_bf16(af[at], bfr[bt], acc[at][bt], 0, 0, 0);
  }

  if (z == 2) {
    #pragma unroll
    for (int at = 0; at < 4; ++at)
      #pragma unroll
      for (int bt = 0; bt < 4; ++bt) {
        int gr = a0 + wa + at * 16 + qd * 4;          // token
        int gc = b0 + wb + bt * 16 + mi;              // feature
        union { bf16 o[4]; uint2 u; } pk;
        #pragma unroll
        for (int r = 0; r < 4; ++r) pk.o[r] = __float2bfloat16(acc[at][bt][r]);
        int bb = gr >> 12, tt = gr & 4095;
        *(uint2*)(O2t + (size_t)bb * 768 * 4096 + (size_t)gc * 4096 + tt) = pk.u;
      }
  } else {
    const float scl = (z == 1) ? SCL : 1.0f;
    bf16* Ob = (z == 0) ? O0 : O1;
    #pragma unroll
    for (int at = 0; at < 4; ++at)
      #pragma unroll
      for (int bt = 0; bt < 4; ++bt) {
        int f0  = a0 + wa + at * 16 + qd * 4;
        int tkn = b0 + wb + bt * 16 + mi;
        union { bf16 o[4]; uint2 u; } pk;
        #pragma unroll
        for (int r = 0; r < 4; ++r) pk.o[r] = __float2bfloat16(acc[at][bt][r] * scl);
        *(uint2*)(Ob + (size_t)tkn * 768 + f0) = pk.u;
      }
  }
}

// ---------------- output projection (Wo staged as A -> float4 stores + bias) -----
__global__ __launch_bounds__(256) void gemm_out(const bf16* __restrict__ ctx,
                                                const bf16* __restrict__ Wo,
                                                float* __restrict__ Cf,
                                                const float* __restrict__ bias) {
  __shared__ bf16 As[2][4096];
  __shared__ bf16 Bs[2][4096];
  const int flat = blockIdx.x;
  const int by = flat / 6, bx = flat % 6;
  const char* Ap = (const char*)Wo;  const int a0 = bx * 128;   // feature rows
  const char* Bp = (const char*)ctx; const int b0 = by * 128;   // token rows
  const int t = threadIdx.x;
  const int w = t >> 6, lane = t & 63;
  const int wa = (w >> 1) * 64, wb = (w & 1) * 64;
  const int mi = lane & 15, qd = lane >> 4;

  int aoff[2], boff[2];
  #pragma unroll
  for (int i = 0; i < 2; ++i) {
    int L = i * 256 + t;
    int row = L >> 2, sl = L & 3, c = sl ^ (row & 3);
    aoff[i] = (a0 + row) * 1536 + c * 16;
    boff[i] = (b0 + row) * 1536 + c * 16;
  }
  const int fsw = (qd ^ (mi & 3)) * 8;

  f32x4 acc[4][4] = {};

  #pragma unroll
  for (int i = 0; i < 2; ++i) {
    GLD16(Ap + aoff[i], &As[0][i * 2048 + w * 512]);
    GLD16(Bp + boff[i], &Bs[0][i * 2048 + w * 512]);
  }

  for (int kk = 0; kk < 24; ++kk) {
    __syncthreads();
    const int par = kk & 1;
    if (kk + 1 < 24) {
      const int np = par ^ 1, kb = (kk + 1) * 64;
      #pragma unroll
      for (int i = 0; i < 2; ++i) {
        GLD16(Ap + aoff[i] + kb, &As[np][i * 2048 + w * 512]);
        GLD16(Bp + boff[i] + kb, &Bs[np][i * 2048 + w * 512]);
      }
    }
    bf16x8 af[4], bfr[4];
    #pragma unroll
    for (int at = 0; at < 4; ++at)
      af[at] = *(const bf16x8*)&As[par][(wa + at * 16 + mi) * 32 + fsw];
    #pragma unroll
    for (int bt = 0; bt < 4; ++bt)
      bfr[bt] = *(const bf16x8*)&Bs[par][(wb + bt * 16 + mi) * 32 + fsw];
    #pragma unroll
    for (int at = 0; at < 4; ++at)
      #pragma unroll
      for (int bt = 0; bt < 4; ++bt)
        acc[at][bt] = __builtin_amdgcn_mfma_f32_16x16x32_bf16(af[at], bfr[bt], acc[at][bt], 0, 0, 0);
  }

  #pragma unroll
  for (int at = 0; at < 4; ++at)
    #pragma unroll
    for (int bt = 0; bt < 4; ++bt) {
      int f0  = a0 + wa + at * 16 + qd * 4;
      int tkn = b0 + wb + bt * 16 + mi;
      float4 bv = *(const float4*)&bias[f0];
      float4 o;
      o.x = acc[at][bt][0] + bv.x; o.y = acc[at][bt][1] + bv.y;
      o.z = acc[at][bt][2] + bv.z; o.w = acc[at][bt][3] + bv.w;
      *(float4*)&Cf[(size_t)tkn * 768 + f0] = o;
    }
}

// ---------------- MFMA flash attention v8: register-resident P -------------------
// Key change vs v7: PV uses 4x K=16 MFMA (v_mfma_f32_16x16x16_bf16) per d-block.
// The swapped-QK^T C layout (sacc[ks][r] = S^T[j=ks*16+qd*4+r][q=mi]) is EXACTLY
// the K=16 B-operand fragment (k=(l>>4)*4+e, n=l&15), so P goes sacc -> exp ->
// pktr -> MFMA entirely in registers. Removes per tile: 4 ds_write_b64 + full
// lgkmcnt(0) drain + 2 ds_read_b128 (the serial P round trip), and the 8KB Pt
// buffer -> LDS 32KB -> 5 blocks/CU (20 waves). V consumed as 16 ds_read_b64
// (conflict-free under the staging XOR swizzle).
__global__ __launch_bounds__(256, 5) void flash_attn(const bf16* __restrict__ Q,
                                                     const bf16* __restrict__ K,
                                                     const bf16* __restrict__ Vt,
                                                     bf16* __restrict__ ctx) {
  __shared__ bf16 Ks[2][4096];
  __shared__ bf16 Vs[2][4096];
  const int t = threadIdx.x;
  const int w = t >> 6, lane = t & 63;
  const int mi = lane & 15, qd = lane >> 4;
  const int bh   = blockIdx.x % 24;
  const int qrev = blockIdx.x / 24;          // heavy blocks (large q0) first
  const int q0 = T_ - 64 - qrev * 64;
  const int b = bh / H_, h = bh % H_;
  const size_t bTD = (size_t)b * T_ * D_;
  const char* Kp = (const char*)(K  + bTD + (size_t)h * HD_);
  const char* Vp = (const char*)(Vt + (size_t)b * D_ * T_ + (size_t)h * HD_ * T_);
  const int qw = q0 + w * 16;                // wave's 16 q-rows

  // staging: 256 threads x 2 chunks x 16B = full 64x64 tile per buffer
  int vkoff[2], vvoff[2];
  #pragma unroll
  for (int i = 0; i < 2; ++i) {
    int L = i * 256 + t;
    int rl = L >> 3, c = (L & 7) ^ (rl & 7);
    vkoff[i] = rl * 1536 + c * 16;
    vvoff[i] = rl * 8192 + c * 16;
  }

  // K reads (QK^T, b128): row j = jt*16+mi, granule (kt*4+qd)^(row&7)
  int fidx[4][2];
  #pragma unroll
  for (int jt = 0; jt < 4; ++jt)
    #pragma unroll
    for (int kt = 0; kt < 2; ++kt)
      fidx[jt][kt] = (jt * 16 + mi) * 64 + (((kt * 4 + qd) ^ (mi & 7)) * 8);

  bf16x8 qf[2];
  const bf16* Qp = Q + bTD + (size_t)h * HD_;
  #pragma unroll
  for (int kt = 0; kt < 2; ++kt)
    qf[kt] = *(const bf16x8*)(Qp + (size_t)(qw + mi) * D_ + kt * 32 + qd * 8);

  f32x4 oacc[4] = {};
  float lst = 0.f;
  const int ntiles = q0 / 64 + 1;

  #pragma unroll
  for (int i = 0; i < 2; ++i) {
    GLD16(Kp + vkoff[i], &Ks[0][i * 2048 + w * 512]);
    GLD16(Vp + vvoff[i], &Vs[0][i * 2048 + w * 512]);
  }

  for (int tt = 0; tt < ntiles; ++tt) {
    __syncthreads();
    const int par = tt & 1;
    if (tt + 1 < ntiles) {
      const size_t j1 = (size_t)(tt + 1) * 64;
      const int np = par ^ 1;
      #pragma unroll
      for (int i = 0; i < 2; ++i) {
        GLD16(Kp + vkoff[i] + j1 * 1536, &Ks[np][i * 2048 + w * 512]);
        GLD16(Vp + vvoff[i] + j1 * 2,    &Vs[np][i * 2048 + w * 512]);
      }
    }
    const int j0 = tt * 64;

    // S^T = K-tile @ Q^T  (C-layout: j = jt*16 + qd*4 + r, q = mi)
    f32x4 sacc[4] = {};
    #pragma unroll
    for (int jt = 0; jt < 4; ++jt)
      #pragma unroll
      for (int kt = 0; kt < 2; ++kt) {
        bf16x8 kf = *(const bf16x8*)&Ks[par][fidx[jt][kt]];
        sacc[jt] = __builtin_amdgcn_mfma_f32_16x16x32_bf16(kf, qf[kt], sacc[jt], 0, 0, 0);
      }

    if (j0 + 63 > qw) {                       // causal mask, diagonal tile only
      const int qg = qw + mi;
      #pragma unroll
      for (int jt = 0; jt < 4; ++jt)
        #pragma unroll
        for (int r = 0; r < 4; ++r) {
          int jg = j0 + jt * 16 + qd * 4 + r;
          if (jg > qg) sacc[jt][r] = -1e30f;
        }
    }

    // p = exp2(s); per-lane partial l; pack to bf16 pairs IN REGISTERS
    s16x4 pB[4];
    #pragma unroll
    for (int jt = 0; jt < 4; ++jt) {
      float p0 = fexp2(sacc[jt][0]);
      float p1 = fexp2(sacc[jt][1]);
      float p2 = fexp2(sacc[jt][2]);
      float p3 = fexp2(sacc[jt][3]);
      lst += (p0 + p1) + (p2 + p3);
      union { uint32_t u[2]; s16x4 s; } pw;
      pw.u[0] = pktr(p0, p1);
      pw.u[1] = pktr(p2, p3);
      pB[jt] = pw.s;
    }

    // O^T += V^T @ P^T via K=16 MFMA: A = V^T[d][j=ks*16+qd*4+e] (b64 reads),
    // B = pB[ks] straight from registers. No LDS transpose round trip.
    #pragma unroll
    for (int ks = 0; ks < 4; ++ks)
      #pragma unroll
      for (int dt = 0; dt < 4; ++dt) {
        int vi = (dt * 16 + mi) * 64 + (((2 * ks + (qd >> 1)) ^ (mi & 7)) * 8) + (qd & 1) * 4;
        s16x4 vf = *(const s16x4*)&Vs[par][vi];
        oacc[dt] = mfma16(vf, pB[ks], oacc[dt]);
      }
  }

  // epilogue: finish l across quads, normalize, packed uint2 stores
  float l = lst;
  l += __shfl_xor(l, 16);
  l += __shfl_xor(l, 32);
  float inv = __builtin_amdgcn_rcpf(l);
  const int qg = qw + mi;
  bf16* cp = ctx + bTD + (size_t)qg * D_ + h * HD_ + qd * 4;
  #pragma unroll
  for (int dt = 0; dt < 4; ++dt) {
    union { bf16 o[4]; uint2 u; } pko;
    #pragma unroll
    for (int r = 0; r < 4; ++r) pko.o[r] = __float2bfloat16(oacc[dt][r] * inv);
    *(uint2*)(cp + dt * 16) = pko.u;
  }
}

// ---------------- launch ----------------
extern "C" void kernel_launch(void* const* d_in, const int* in_sizes, int n_in,
                              void* d_out, int out_size, void* d_ws, size_t ws_size,
                              hipStream_t stream) {
  const float* x  = (const float*)d_in[0];
  const float* Wq = (const float*)d_in[1];
  const float* Wk = (const float*)d_in[2];
  const float* Wv = (const float*)d_in[3];
  const float* Wo = (const float*)d_in[4];
  const float* bo = (const float*)d_in[5];
  float* out = (float*)d_out;

  char* ws = (char*)d_ws;
  const size_t SZ  = (size_t)M_ * D_ * 2;
  const size_t WSZ = (size_t)D_ * D_ * 2;
  bf16* xb   = (bf16*)(ws);                 // [M, D]
  bf16* Qb   = (bf16*)(ws + 1 * SZ);        // [B,T,D]
  bf16* Kb   = (bf16*)(ws + 2 * SZ);        // [B,T,D], pre-scaled by SCL
  bf16* Vtg  = (bf16*)(ws + 3 * SZ);        // [B][D][T]
  bf16* ctxb = (bf16*)(ws + 4 * SZ);        // [B,T,D]
  bf16* Wqb  = (bf16*)(ws + 5 * SZ);
  bf16* Wkb  = (bf16*)(ws + 5 * SZ + 1 * WSZ);
  bf16* Wvb  = (bf16*)(ws + 5 * SZ + 2 * WSZ);
  bf16* Wob  = (bf16*)(ws + 5 * SZ + 3 * WSZ);

  cvt_all<<<6144 + 4 * 576, 256, 0, stream>>>(x, Wq, Wk, Wv, Wo, xb, Wqb, Wkb, Wvb, Wob);

  gemm_qkv<<<1152, 256, 0, stream>>>(xb, Wqb, Wkb, Wvb, Qb, Kb, Vtg);

  flash_attn<<<(T_ / 64) * B_ * H_, 256, 0, stream>>>(Qb, Kb, Vtg, ctxb);

  gemm_out<<<384, 256, 0, stream>>>(ctxb, Wob, out, bo);
}

// Round 3
// 241.959 us; speedup vs baseline: 1.0112x; 1.0112x over previous
//
#include <hip/hip_runtime.h>
#include <hip/hip_bf16.h>
#include <cstdint>
#include <cstddef>

#define B_  2
#define T_  4096
#define D_  768
#define H_  12
#define HD_ 64
#define M_  (B_*T_)   // 8192 rows

#define SCL 0.18033688f   // (1/sqrt(64)) * log2(e): folded into K projection

typedef __bf16 bf16x8 __attribute__((ext_vector_type(8)));
typedef float  f32x4  __attribute__((ext_vector_type(4)));
typedef short  s16x4  __attribute__((ext_vector_type(4)));
using bf16 = __hip_bfloat16;

__device__ inline float fexp2(float x) {
  float r; asm("v_exp_f32 %0, %1" : "=v"(r) : "v"(x)); return r;
}
__device__ inline uint32_t fu(float x) { union { float f; uint32_t u; } c; c.f = x; return c.u; }
__device__ inline uint32_t pktr(float a, float b) {   // truncated bf16 pair, 1 v_perm
  return __builtin_amdgcn_perm(fu(b), fu(a), 0x07060302);
}
// K=16 bf16 MFMA: B-operand fragment layout == swapped-QK^T C layout (k=qd*4+e),
// so P feeds PV straight from registers (no LDS transpose round trip).
__device__ inline f32x4 mfma16(s16x4 a, s16x4 b, f32x4 c) {
#if __has_builtin(__builtin_amdgcn_mfma_f32_16x16x16bf16_1k)
  return __builtin_amdgcn_mfma_f32_16x16x16bf16_1k(a, b, c, 0, 0, 0);
#else
  asm("v_mfma_f32_16x16x16_bf16 %0, %1, %2, %0" : "+v"(c) : "v"(a), "v"(b));
  return c;
#endif
}
#define GLD16(g, l) __builtin_amdgcn_global_load_lds( \
    (const __attribute__((address_space(1))) uint32_t*)(const void*)(g), \
    (__attribute__((address_space(3))) uint32_t*)(void*)(l), 16, 0, 0)

// ---------------- fp32 -> bf16 conversion (x + 4 weights, exact 1D grid) ---------
__global__ void cvt_all(const float* __restrict__ x,
                        const float* __restrict__ w0, const float* __restrict__ w1,
                        const float* __restrict__ w2, const float* __restrict__ w3,
                        bf16* __restrict__ xd,
                        bf16* __restrict__ d0, bf16* __restrict__ d1,
                        bf16* __restrict__ d2, bf16* __restrict__ d3) {
  int blk = blockIdx.x;
  const float* s; bf16* d; int i;
  if (blk < 6144) {                       // x: 6144*256 == M*D/4 exactly
    s = x; d = xd; i = blk * 256 + threadIdx.x;
  } else {                                // weights: 576*256 == D*D/4 exactly
    int q = blk - 6144, which = q / 576, rb = q % 576;
    switch (which) {
      case 0: s = w0; d = d0; break;
      case 1: s = w1; d = d1; break;
      case 2: s = w2; d = d2; break;
      default: s = w3; d = d3; break;
    }
    i = rb * 256 + threadIdx.x;
  }
  float4 v = ((const float4*)s)[i];
  union { bf16 o[4]; uint2 u; } pk;
  pk.o[0] = __float2bfloat16(v.x); pk.o[1] = __float2bfloat16(v.y);
  pk.o[2] = __float2bfloat16(v.z); pk.o[3] = __float2bfloat16(v.w);
  *(uint2*)(d + 4 * (size_t)i) = pk.u;
}

// ---------------- unified QKV GEMM, single K-loop path ---------------------------
__global__ __launch_bounds__(256) void gemm_qkv(const bf16* __restrict__ x,
                                                const bf16* __restrict__ W0,
                                                const bf16* __restrict__ W1,
                                                const bf16* __restrict__ W2,
                                                bf16* __restrict__ O0,
                                                bf16* __restrict__ O1,
                                                bf16* __restrict__ O2t) {
  __shared__ bf16 As[2][4096];
  __shared__ bf16 Bs[2][4096];
  const int flat = blockIdx.x;
  const int by = flat / 18;            // token tile (m)
  const int rr = flat % 18;
  const int z  = rr / 6;
  const int bx = rr % 6;               // feature tile (n)
  const bf16* Wz = (z == 0) ? W0 : ((z == 1) ? W1 : W2);
  const char* Ap; const char* Bp; int a0, b0;
  if (z == 2) { Ap = (const char*)x;  a0 = by * 128; Bp = (const char*)Wz; b0 = bx * 128; }
  else        { Ap = (const char*)Wz; a0 = bx * 128; Bp = (const char*)x;  b0 = by * 128; }
  const int t = threadIdx.x;
  const int w = t >> 6, lane = t & 63;
  const int wa = (w >> 1) * 64, wb = (w & 1) * 64;
  const int mi = lane & 15, qd = lane >> 4;

  int aoff[2], boff[2];
  #pragma unroll
  for (int i = 0; i < 2; ++i) {
    int L = i * 256 + t;
    int row = L >> 2, sl = L & 3, c = sl ^ (row & 3);
    aoff[i] = (a0 + row) * 1536 + c * 16;
    boff[i] = (b0 + row) * 1536 + c * 16;
  }
  const int fsw = (qd ^ (mi & 3)) * 8;

  f32x4 acc[4][4] = {};

  #pragma unroll
  for (int i = 0; i < 2; ++i) {
    GLD16(Ap + aoff[i], &As[0][i * 2048 + w * 512]);
    GLD16(Bp + boff[i], &Bs[0][i * 2048 + w * 512]);
  }

  for (int kk = 0; kk < 24; ++kk) {
    __syncthreads();
    const int par = kk & 1;
    if (kk + 1 < 24) {
      const int np = par ^ 1, kb = (kk + 1) * 64;
      #pragma unroll
      for (int i = 0; i < 2; ++i) {
        GLD16(Ap + aoff[i] + kb, &As[np][i * 2048 + w * 512]);
        GLD16(Bp + boff[i] + kb, &Bs[np][i * 2048 + w * 512]);
      }
    }
    bf16x8 af[4], bfr[4];
    #pragma unroll
    for (int at = 0; at < 4; ++at)
      af[at] = *(const bf16x8*)&As[par][(wa + at * 16 + mi) * 32 + fsw];
    #pragma unroll
    for (int bt = 0; bt < 4; ++bt)
      bfr[bt] = *(const bf16x8*)&Bs[par][(wb + bt * 16 + mi) * 32 + fsw];
    #pragma unroll
    for (int at = 0; at < 4; ++at)
      #pragma unroll
      for (int bt = 0; bt < 4; ++bt)
        acc[at][bt] = __builtin_amdgcn_mfma_f32_16x16x32_bf16(af[at], bfr[bt], acc[at][bt], 0, 0, 0);
  }

  if (z == 2) {
    #pragma unroll
    for (int at = 0; at < 4; ++at)
      #pragma unroll
      for (int bt = 0; bt < 4; ++bt) {
        int gr = a0 + wa + at * 16 + qd * 4;          // token
        int gc = b0 + wb + bt * 16 + mi;              // feature
        union { bf16 o[4]; uint2 u; } pk;
        #pragma unroll
        for (int r = 0; r < 4; ++r) pk.o[r] = __float2bfloat16(acc[at][bt][r]);
        int bb = gr >> 12, tt = gr & 4095;
        // half-swap token quads within each 16B granule for feature rows with
        // bit3 set: gives the flash PV b64 reads a (mi>>3)-dependent bank bit
        // (conflict-free 16-lane phases). Read side XORs the same bit.
        int ttw = tt ^ (((gc >> 3) & 1) << 2);
        *(uint2*)(O2t + (size_t)bb * 768 * 4096 + (size_t)gc * 4096 + ttw) = pk.u;
      }
  } else {
    const float scl = (z == 1) ? SCL : 1.0f;
    bf16* Ob = (z == 0) ? O0 : O1;
    #pragma unroll
    for (int at = 0; at < 4; ++at)
      #pragma unroll
      for (int bt = 0; bt < 4; ++bt) {
        int f0  = a0 + wa + at * 16 + qd * 4;
        int tkn = b0 + wb + bt * 16 + mi;
        union { bf16 o[4]; uint2 u; } pk;
        #pragma unroll
        for (int r = 0; r < 4; ++r) pk.o[r] = __float2bfloat16(acc[at][bt][r] * scl);
        *(uint2*)(Ob + (size_t)tkn * 768 + f0) = pk.u;
      }
  }
}

// ---------------- output projection (Wo staged as A -> float4 stores + bias) -----
__global__ __launch_bounds__(256) void gemm_out(const bf16* __restrict__ ctx,
                                                const bf16* __restrict__ Wo,
                                                float* __restrict__ Cf,
                                                const float* __restrict__ bias) {
  __shared__ bf16 As[2][4096];
  __shared__ bf16 Bs[2][4096];
  const int flat = blockIdx.x;
  const int by = flat / 6, bx = flat % 6;
  const char* Ap = (const char*)Wo;  const int a0 = bx * 128;   // feature rows
  const char* Bp = (const char*)ctx; const int b0 = by * 128;   // token rows
  const int t = threadIdx.x;
  const int w = t >> 6, lane = t & 63;
  const int wa = (w >> 1) * 64, wb = (w & 1) * 64;
  const int mi = lane & 15, qd = lane >> 4;

  int aoff[2], boff[2];
  #pragma unroll
  for (int i = 0; i < 2; ++i) {
    int L = i * 256 + t;
    int row = L >> 2, sl = L & 3, c = sl ^ (row & 3);
    aoff[i] = (a0 + row) * 1536 + c * 16;
    boff[i] = (b0 + row) * 1536 + c * 16;
  }
  const int fsw = (qd ^ (mi & 3)) * 8;

  f32x4 acc[4][4] = {};

  #pragma unroll
  for (int i = 0; i < 2; ++i) {
    GLD16(Ap + aoff[i], &As[0][i * 2048 + w * 512]);
    GLD16(Bp + boff[i], &Bs[0][i * 2048 + w * 512]);
  }

  for (int kk = 0; kk < 24; ++kk) {
    __syncthreads();
    const int par = kk & 1;
    if (kk + 1 < 24) {
      const int np = par ^ 1, kb = (kk + 1) * 64;
      #pragma unroll
      for (int i = 0; i < 2; ++i) {
        GLD16(Ap + aoff[i] + kb, &As[np][i * 2048 + w * 512]);
        GLD16(Bp + boff[i] + kb, &Bs[np][i * 2048 + w * 512]);
      }
    }
    bf16x8 af[4], bfr[4];
    #pragma unroll
    for (int at = 0; at < 4; ++at)
      af[at] = *(const bf16x8*)&As[par][(wa + at * 16 + mi) * 32 + fsw];
    #pragma unroll
    for (int bt = 0; bt < 4; ++bt)
      bfr[bt] = *(const bf16x8*)&Bs[par][(wb + bt * 16 + mi) * 32 + fsw];
    #pragma unroll
    for (int at = 0; at < 4; ++at)
      #pragma unroll
      for (int bt = 0; bt < 4; ++bt)
        acc[at][bt] = __builtin_amdgcn_mfma_f32_16x16x32_bf16(af[at], bfr[bt], acc[at][bt], 0, 0, 0);
  }

  #pragma unroll
  for (int at = 0; at < 4; ++at)
    #pragma unroll
    for (int bt = 0; bt < 4; ++bt) {
      int f0  = a0 + wa + at * 16 + qd * 4;
      int tkn = b0 + wb + bt * 16 + mi;
      float4 bv = *(const float4*)&bias[f0];
      float4 o;
      o.x = acc[at][bt][0] + bv.x; o.y = acc[at][bt][1] + bv.y;
      o.z = acc[at][bt][2] + bv.z; o.w = acc[at][bt][3] + bv.w;
      *(float4*)&Cf[(size_t)tkn * 768 + f0] = o;
    }
}

// ---------------- MFMA flash attention v9: register P + conflict-free V ----------
// v8 + the V bank fix: PV b64 reads previously had lanes mi and mi+8 in the same
// bank pair every 16-lane phase (bank = 4g + 2(qd&1), no mi>>3 term) -> every V
// read cost 2x (12.78M conflict cycles/dispatch, matches 16 reads x 4 extra
// cycles x 200k tile-waves). V^T global layout now half-swaps token quads within
// each 16B granule for feature rows with bit3 set; the read picks its quad at
// (qd&1)^((mi>>3)&1) -> all 32 banks covered per phase.
__global__ __launch_bounds__(256, 5) void flash_attn(const bf16* __restrict__ Q,
                                                     const bf16* __restrict__ K,
                                                     const bf16* __restrict__ Vt,
                                                     bf16* __restrict__ ctx) {
  __shared__ bf16 Ks[2][4096];
  __shared__ bf16 Vs[2][4096];
  const int t = threadIdx.x;
  const int w = t >> 6, lane = t & 63;
  const int mi = lane & 15, qd = lane >> 4;
  const int bh   = blockIdx.x % 24;
  const int qrev = blockIdx.x / 24;          // heavy blocks (large q0) first
  const int q0 = T_ - 64 - qrev * 64;
  const int b = bh / H_, h = bh % H_;
  const size_t bTD = (size_t)b * T_ * D_;
  const char* Kp = (const char*)(K  + bTD + (size_t)h * HD_);
  const char* Vp = (const char*)(Vt + (size_t)b * D_ * T_ + (size_t)h * HD_ * T_);
  const int qw = q0 + w * 16;                // wave's 16 q-rows

  // staging: 256 threads x 2 chunks x 16B = full 64x64 tile per buffer
  int vkoff[2], vvoff[2];
  #pragma unroll
  for (int i = 0; i < 2; ++i) {
    int L = i * 256 + t;
    int rl = L >> 3, c = (L & 7) ^ (rl & 7);
    vkoff[i] = rl * 1536 + c * 16;
    vvoff[i] = rl * 8192 + c * 16;
  }

  // K reads (QK^T, b128): row j = jt*16+mi, granule (kt*4+qd)^(row&7)
  int fidx[4][2];
  #pragma unroll
  for (int jt = 0; jt < 4; ++jt)
    #pragma unroll
    for (int kt = 0; kt < 2; ++kt)
      fidx[jt][kt] = (jt * 16 + mi) * 64 + (((kt * 4 + qd) ^ (mi & 7)) * 8);

  // V reads (PV, b64): row d = dt*16+mi, granule (2ks+(qd>>1))^(mi&7),
  // quad (qd&1)^((mi>>3)&1)  [matches the store-side half-swap]
  int vbase[4];
  #pragma unroll
  for (int ks = 0; ks < 4; ++ks)
    vbase[ks] = (((2 * ks + (qd >> 1)) ^ (mi & 7)) * 8) +
                (((qd & 1) ^ ((mi >> 3) & 1)) * 4) + mi * 64;

  bf16x8 qf[2];
  const bf16* Qp = Q + bTD + (size_t)h * HD_;
  #pragma unroll
  for (int kt = 0; kt < 2; ++kt)
    qf[kt] = *(const bf16x8*)(Qp + (size_t)(qw + mi) * D_ + kt * 32 + qd * 8);

  f32x4 oacc[4] = {};
  float lst = 0.f;
  const int ntiles = q0 / 64 + 1;

  #pragma unroll
  for (int i = 0; i < 2; ++i) {
    GLD16(Kp + vkoff[i], &Ks[0][i * 2048 + w * 512]);
    GLD16(Vp + vvoff[i], &Vs[0][i * 2048 + w * 512]);
  }

  for (int tt = 0; tt < ntiles; ++tt) {
    __syncthreads();
    const int par = tt & 1;
    if (tt + 1 < ntiles) {
      const size_t j1 = (size_t)(tt + 1) * 64;
      const int np = par ^ 1;
      #pragma unroll
      for (int i = 0; i < 2; ++i) {
        GLD16(Kp + vkoff[i] + j1 * 1536, &Ks[np][i * 2048 + w * 512]);
        GLD16(Vp + vvoff[i] + j1 * 2,    &Vs[np][i * 2048 + w * 512]);
      }
    }
    const int j0 = tt * 64;

    // S^T = K-tile @ Q^T  (C-layout: j = jt*16 + qd*4 + r, q = mi)
    f32x4 sacc[4] = {};
    #pragma unroll
    for (int jt = 0; jt < 4; ++jt)
      #pragma unroll
      for (int kt = 0; kt < 2; ++kt) {
        bf16x8 kf = *(const bf16x8*)&Ks[par][fidx[jt][kt]];
        sacc[jt] = __builtin_amdgcn_mfma_f32_16x16x32_bf16(kf, qf[kt], sacc[jt], 0, 0, 0);
      }

    if (j0 + 63 > qw) {                       // causal mask, diagonal tile only
      const int qg = qw + mi;
      #pragma unroll
      for (int jt = 0; jt < 4; ++jt)
        #pragma unroll
        for (int r = 0; r < 4; ++r) {
          int jg = j0 + jt * 16 + qd * 4 + r;
          if (jg > qg) sacc[jt][r] = -1e30f;
        }
    }

    // p = exp2(s); per-lane partial l; pack to bf16 pairs IN REGISTERS
    s16x4 pB[4];
    #pragma unroll
    for (int jt = 0; jt < 4; ++jt) {
      float p0 = fexp2(sacc[jt][0]);
      float p1 = fexp2(sacc[jt][1]);
      float p2 = fexp2(sacc[jt][2]);
      float p3 = fexp2(sacc[jt][3]);
      lst += (p0 + p1) + (p2 + p3);
      union { uint32_t u[2]; s16x4 s; } pw;
      pw.u[0] = pktr(p0, p1);
      pw.u[1] = pktr(p2, p3);
      pB[jt] = pw.s;
    }

    // O^T += V^T @ P^T via K=16 MFMA: A = V^T[d][j=ks*16+qd*4+e] (b64 reads),
    // B = pB[ks] straight from registers. No LDS transpose round trip.
    #pragma unroll
    for (int ks = 0; ks < 4; ++ks)
      #pragma unroll
      for (int dt = 0; dt < 4; ++dt) {
        s16x4 vf = *(const s16x4*)&Vs[par][vbase[ks] + dt * 1024];
        oacc[dt] = mfma16(vf, pB[ks], oacc[dt]);
      }
  }

  // epilogue: finish l across quads, normalize, packed uint2 stores
  float l = lst;
  l += __shfl_xor(l, 16);
  l += __shfl_xor(l, 32);
  float inv = __builtin_amdgcn_rcpf(l);
  const int qg = qw + mi;
  bf16* cp = ctx + bTD + (size_t)qg * D_ + h * HD_ + qd * 4;
  #pragma unroll
  for (int dt = 0; dt < 4; ++dt) {
    union { bf16 o[4]; uint2 u; } pko;
    #pragma unroll
    for (int r = 0; r < 4; ++r) pko.o[r] = __float2bfloat16(oacc[dt][r] * inv);
    *(uint2*)(cp + dt * 16) = pko.u;
  }
}

// ---------------- launch ----------------
extern "C" void kernel_launch(void* const* d_in, const int* in_sizes, int n_in,
                              void* d_out, int out_size, void* d_ws, size_t ws_size,
                              hipStream_t stream) {
  const float* x  = (const float*)d_in[0];
  const float* Wq = (const float*)d_in[1];
  const float* Wk = (const float*)d_in[2];
  const float* Wv = (const float*)d_in[3];
  const float* Wo = (const float*)d_in[4];
  const float* bo = (const float*)d_in[5];
  float* out = (float*)d_out;

  char* ws = (char*)d_ws;
  const size_t SZ  = (size_t)M_ * D_ * 2;
  const size_t WSZ = (size_t)D_ * D_ * 2;
  bf16* xb   = (bf16*)(ws);                 // [M, D]
  bf16* Qb   = (bf16*)(ws + 1 * SZ);        // [B,T,D]
  bf16* Kb   = (bf16*)(ws + 2 * SZ);        // [B,T,D], pre-scaled by SCL
  bf16* Vtg  = (bf16*)(ws + 3 * SZ);        // [B][D][T], granule half-swap on bit3 rows
  bf16* ctxb = (bf16*)(ws + 4 * SZ);        // [B,T,D]
  bf16* Wqb  = (bf16*)(ws + 5 * SZ);
  bf16* Wkb  = (bf16*)(ws + 5 * SZ + 1 * WSZ);
  bf16* Wvb  = (bf16*)(ws + 5 * SZ + 2 * WSZ);
  bf16* Wob  = (bf16*)(ws + 5 * SZ + 3 * WSZ);

  cvt_all<<<6144 + 4 * 576, 256, 0, stream>>>(x, Wq, Wk, Wv, Wo, xb, Wqb, Wkb, Wvb, Wob);

  gemm_qkv<<<1152, 256, 0, stream>>>(xb, Wqb, Wkb, Wvb, Qb, Kb, Vtg);

  flash_attn<<<(T_ / 64) * B_ * H_, 256, 0, stream>>>(Qb, Kb, Vtg, ctxb);

  gemm_out<<<384, 256, 0, stream>>>(ctxb, Wob, out, bo);
}